// Round 1
// baseline (27.457 us; speedup 1.0000x reference)
//
#include <hip/hip_runtime.h>
#include <hip/hip_bf16.h>

// Smolyak sparse-grid integration of f(x) = W@x + b over DIM=6, LEVEL=5.
// f is linear => out = W*S + b*Wsum with S = sum_p w_p x_p (6 floats),
// Wsum = sum_p w_p. 210 terms, 6430 quadrature points total -> kernel A
// computes the 7 scalars; kernel B does the rank-1 epilogue over 65536 rows.

#define NDIM 6
#define OUTN 65536
#define RULE_TOTAL 35   // 1+3+5+9+17 nodes across levels 1..5

__device__ __forceinline__ float pick6(const float a[NDIM], int i) {
    // branchless select: avoids runtime-indexed local array -> scratch
    float r = a[0];
    r = (i == 1) ? a[1] : r;
    r = (i == 2) ? a[2] : r;
    r = (i == 3) ? a[3] : r;
    r = (i == 4) ? a[4] : r;
    r = (i == 5) ? a[5] : r;
    return r;
}

// ---- Kernel A: reduce all (term, point) pairs to S[6] + Wsum ----
// One block, 256 threads; thread t handles terms t, t+256, ...
__global__ __launch_bounds__(256) void smolyak_moments_kernel(
    const int* __restrict__ offs,    // [NT][6] rule offsets (sorted-axis order)
    const int* __restrict__ lens,    // [NT][6] rule lengths (sorted-axis order)
    const int* __restrict__ invp,    // [NT][6] inverse axis permutation
    const int* __restrict__ npts,    // [NT]
    const float* __restrict__ nodes, // [35]
    const float* __restrict__ wts,   // [35]
    int NT,
    float* __restrict__ ws)          // out: ws[0..5] = S, ws[6] = Wsum
{
    __shared__ float s_nodes[RULE_TOTAL];
    __shared__ float s_wts[RULE_TOTAL];
    if (threadIdx.x < RULE_TOTAL) {
        s_nodes[threadIdx.x] = nodes[threadIdx.x];
        s_wts[threadIdx.x]   = wts[threadIdx.x];
    }
    __syncthreads();

    float S[NDIM] = {0.f, 0.f, 0.f, 0.f, 0.f, 0.f};
    float wsum = 0.f;

    for (int t = threadIdx.x; t < NT; t += 256) {
        int o[NDIM], L[NDIM], P[NDIM];
        #pragma unroll
        for (int i = 0; i < NDIM; ++i) {
            o[i] = offs[t * NDIM + i];
            L[i] = lens[t * NDIM + i];
            P[i] = invp[t * NDIM + i];
        }
        const int np = npts[t];

        // per-sorted-axis first moments for this term (static indexing only)
        float St[NDIM] = {0.f, 0.f, 0.f, 0.f, 0.f, 0.f};
        int loc[NDIM] = {0, 0, 0, 0, 0, 0};

        for (int p = 0; p < np; ++p) {
            float w = 1.f;
            float x[NDIM];
            #pragma unroll
            for (int i = 0; i < NDIM; ++i) {
                const int r = o[i] + loc[i];
                w *= s_wts[r];
                x[i] = s_nodes[r];
            }
            wsum += w;
            #pragma unroll
            for (int i = 0; i < NDIM; ++i) St[i] += w * x[i];

            // odometer increment, last axis fastest (strides[i] = prod lens[i+1:])
            #pragma unroll
            for (int i = NDIM - 1; i >= 0; --i) {
                ++loc[i];
                if (loc[i] < L[i]) break;
                loc[i] = 0;
            }
        }

        // un-permute: output dim d gets sorted axis invp[d]
        #pragma unroll
        for (int d = 0; d < NDIM; ++d) S[d] += pick6(St, P[d]);
    }

    // deterministic block tree-reduction of 7 scalars
    __shared__ float red[256];
    float vals[7] = {S[0], S[1], S[2], S[3], S[4], S[5], wsum};
    #pragma unroll
    for (int k = 0; k < 7; ++k) {
        __syncthreads();
        red[threadIdx.x] = vals[k];
        __syncthreads();
        for (int s = 128; s > 0; s >>= 1) {
            if (threadIdx.x < (unsigned)s) red[threadIdx.x] += red[threadIdx.x + s];
            __syncthreads();
        }
        if (threadIdx.x == 0) ws[k] = red[0];
    }
}

// ---- Kernel B: out[i] = dot(W[i,:], S) + b[i]*Wsum ----
// 256 rows per block; W staged through LDS with float4 coalesced loads.
__global__ __launch_bounds__(256) void smolyak_epilogue_kernel(
    const float* __restrict__ W,   // [OUTN][6]
    const float* __restrict__ b,   // [OUTN]
    const float* __restrict__ ws,  // S[6], Wsum
    float* __restrict__ out)       // [OUTN]
{
    __shared__ float sS[8];
    __shared__ float4 sw4[384];    // 256 rows * 6 floats = 1536 floats
    if (threadIdx.x < 7) sS[threadIdx.x] = ws[threadIdx.x];

    const float4* Wv = reinterpret_cast<const float4*>(W) + (size_t)blockIdx.x * 384;
    #pragma unroll
    for (int k = 0; k < 2; ++k) {
        const int idx = threadIdx.x + k * 256;
        if (idx < 384) sw4[idx] = Wv[idx];
    }
    __syncthreads();

    const int i = blockIdx.x * 256 + threadIdx.x;
    const float* row = reinterpret_cast<const float*>(sw4) + threadIdx.x * 6;

    float acc = b[i] * sS[6];
    #pragma unroll
    for (int j = 0; j < NDIM; ++j) acc = fmaf(row[j], sS[j], acc);
    out[i] = acc;
}

extern "C" void kernel_launch(void* const* d_in, const int* in_sizes, int n_in,
                              void* d_out, int out_size, void* d_ws, size_t ws_size,
                              hipStream_t stream) {
    const int*   offs  = (const int*)d_in[0];   // batched_term_rule_offsets [NT][6]
    const int*   lens  = (const int*)d_in[1];   // batched_term_rule_lengths [NT][6]
    // d_in[2] = strides (unused: odometer enumeration reproduces them exactly)
    const int*   invp  = (const int*)d_in[3];   // inverse axis permutations [NT][6]
    const int*   npts  = (const int*)d_in[4];   // term_num_points [NT]
    const float* nodes = (const float*)d_in[5]; // rule_nodes [35]
    const float* wts   = (const float*)d_in[6]; // rule_weights [35]
    const float* W     = (const float*)d_in[7]; // [65536][6]
    const float* b     = (const float*)d_in[8]; // [65536]
    float*       out   = (float*)d_out;
    float*       ws    = (float*)d_ws;          // 7 floats of scratch

    const int NT = in_sizes[4];

    smolyak_moments_kernel<<<1, 256, 0, stream>>>(offs, lens, invp, npts,
                                                  nodes, wts, NT, ws);

    const int nblocks = out_size / 256;         // 65536 / 256 = 256
    smolyak_epilogue_kernel<<<nblocks, 256, 0, stream>>>(W, b, ws, out);
}